// Round 5
// baseline (293.392 us; speedup 1.0000x reference)
//
#include <hip/hip_runtime.h>
#include <math.h>

// ---------------------------------------------------------------------------
// Only sample 0 of the batch affects the loss (features[0], cap[0]).
// ONE kernel, grid 256 (= CU count, all blocks co-resident), role-partitioned:
//   blocks 0..7    RNN (8x256, 64 rows each, W_h in VGPRs). Block 0 first
//                  zeroes vacc/asum/d_out/counters, poisons U/H/feat with
//                  0xAA itself, then release-stores MAGIC -> design does not
//                  depend on initial d_ws contents.
//   blocks 8..70   loss block t: computes U[t] (atomic stores), then polls
//                  H row t via ONE sentinel cell + s_sleep backoff (low MALL
//                  traffic), computes y_t/squared error, atomicAdd to loss.
//   blocks 71..78  FC: wait vlad_done==64, normalize vlad, 64 feat rows each.
//   blocks 79..142 conv2+relu+pool fused with NetVLAD softmax+accumulate;
//                  wait conv_done==113; tick vlad_done.
//   blocks 143..255 conv1+relu+pool -> p1 (atomic stores); tick conv_done
//                  (after MAGIC gate).
// All cross-block traffic via relaxed agent-scope atomics (MALL-coherent).
// RNN step: double-buffered LDS (1 barrier/step), concurrent 2-cell poll,
// own-block cells forwarded through LDS, U prefetched one step ahead.
// ---------------------------------------------------------------------------

#define POISON 0xAAAAAAAAu
#define MAGIC  0x13579BDFu

__device__ __forceinline__ float sigmoidf_(float x) {
  return 1.0f / (1.0f + __expf(-x));
}
__device__ __forceinline__ unsigned uld(const unsigned* p) {
  return __hip_atomic_load(p, __ATOMIC_RELAXED, __HIP_MEMORY_SCOPE_AGENT);
}
__device__ __forceinline__ float fld(const float* p) {
  return __hip_atomic_load(p, __ATOMIC_RELAXED, __HIP_MEMORY_SCOPE_AGENT);
}
__device__ __forceinline__ void fst(float* p, float v) {
  __hip_atomic_store(p, v, __ATOMIC_RELAXED, __HIP_MEMORY_SCOPE_AGENT);
}
__device__ __forceinline__ void ust(unsigned* p, unsigned v) {
  __hip_atomic_store(p, v, __ATOMIC_RELAXED, __HIP_MEMORY_SCOPE_AGENT);
}

__global__ __launch_bounds__(256, 1)
void k_fused(const float* __restrict__ img,  const float* __restrict__ cap,
             const float* __restrict__ c1w,  const float* __restrict__ c1b,
             const float* __restrict__ c2w,  const float* __restrict__ c2b,
             const float* __restrict__ cent, const float* __restrict__ nvw,
             const float* __restrict__ nvb,  const float* __restrict__ fcw,
             const float* __restrict__ fcb,  const float* __restrict__ hidw,
             const float* __restrict__ hidb, const float* __restrict__ outw,
             const float* __restrict__ outb,
             float* __restrict__ p1,   float* __restrict__ vacc,
             float* __restrict__ asum, float* __restrict__ feat,
             float* __restrict__ U,    float* __restrict__ H,
             unsigned* __restrict__ flags, float* __restrict__ loss) {
  __shared__ __align__(16) float smem[12832];
  const int bx  = blockIdx.x;
  const int tid = threadIdx.x;
  unsigned* flag_ready = flags + 0;
  unsigned* conv_done  = flags + 1;
  unsigned* vlad_done  = flags + 2;

  // ========================== RNN: blocks 0..7 ==========================
  if (bx < 8) {
    if (bx == 0) {
      // ---- init: zero accumulators/counters, poison U/H/feat ----
      for (int i = tid; i < 1024; i += 256) fst(vacc + i, 0.f);
      if (tid < 64) fst(asum + tid, 0.f);
      if (tid == 0) { fst(loss, 0.f); ust(conv_done, 0u); ust(vlad_done, 0u); }
      unsigned* Uu = (unsigned*)U;
      unsigned* Hu = (unsigned*)H;
      unsigned* Fu = (unsigned*)feat;
      for (int i = tid; i < 63 * 512; i += 256) ust(Uu + i, POISON);
      for (int i = tid; i < 63 * 512; i += 256) ust(Hu + i, POISON);
      if (tid < 256) { ust(Fu + tid, POISON); ust(Fu + tid + 256, POISON); }
      __syncthreads();
      if (tid == 0)
        __hip_atomic_store(flag_ready, MAGIC, __ATOMIC_RELEASE,
                           __HIP_MEMORY_SCOPE_AGENT);
    }
    const int r   = tid >> 2;
    const int cg  = tid & 3;
    const int row = bx * 64 + r;
    float4 wr[32];
    const float4* wp = (const float4*)(hidw + row * 812 + 300 + cg * 128);
    #pragma unroll
    for (int i = 0; i < 32; ++i) wr[i] = wp[i];
    if (bx != 0) {   // gate on init (block 0 is ordered by construction)
      if (tid == 0) {
        while (__hip_atomic_load(flag_ready, __ATOMIC_ACQUIRE,
                                 __HIP_MEMORY_SCOPE_AGENT) != MAGIC)
          __builtin_amdgcn_s_sleep(2);
      }
      __syncthreads();
    }
    float* buf0 = smem;          // 544 floats, swizzled (chunk k at k*136)
    float* buf1 = smem + 544;
    const int w0 = (tid >> 7) * 136 + (tid & 127);
    const int w1 = ((tid + 256) >> 7) * 136 + ((tid + 256) & 127);
    const int wown = (row >> 7) * 136 + (row & 127);
    const bool own0 = ((tid >> 6) == bx);
    const bool own1 = (((tid + 256) >> 6) == bx);
    // ---- stage feat into buf0 (data-as-flag poll) ----
    {
      const unsigned* fu = (const unsigned*)feat;
      unsigned f0, f1;
      do {
        f0 = uld(fu + tid);
        f1 = uld(fu + tid + 256);
      } while (f0 == POISON || f1 == POISON);
      buf0[w0] = __uint_as_float(f0);
      buf0[w1] = __uint_as_float(f1);
    }
    unsigned upat = 0;
    if (cg == 0) upat = uld((const unsigned*)(U + row));   // prefetch t=0
    __syncthreads();
    unsigned* Hu = (unsigned*)H;
    for (int t = 0; t < 63; ++t) {
      const float* bufc = (t & 1) ? buf1 : buf0;
      const float* rb = bufc + cg * 136;
      float acc = 0.f;
      #pragma unroll
      for (int i = 0; i < 32; ++i) {
        float4 h4 = *(const float4*)(rb + i * 4);
        acc = fmaf(wr[i].x, h4.x, acc);
        acc = fmaf(wr[i].y, h4.y, acc);
        acc = fmaf(wr[i].z, h4.z, acc);
        acc = fmaf(wr[i].w, h4.w, acc);
      }
      acc += __shfl_xor(acc, 1);
      acc += __shfl_xor(acc, 2);
      float hn = 0.f;
      if (cg == 0) {
        while (upat == POISON) upat = uld((const unsigned*)(U + t * 512 + row));
        hn = sigmoidf_(acc + __uint_as_float(upat));
        fst(H + t * 512 + row, hn);
      }
      if (t < 62) {
        float* bufn = (t & 1) ? buf0 : buf1;
        if (cg == 0) {
          bufn[wown] = hn;                       // own row via LDS, no RT
          upat = uld((const unsigned*)(U + (t + 1) * 512 + row));  // prefetch
        }
        const unsigned* src = Hu + t * 512;
        unsigned a0 = 0, a1 = 0;
        do {                                     // both polls in flight
          if (!own0) a0 = uld(src + tid);
          if (!own1) a1 = uld(src + tid + 256);
        } while ((!own0 && a0 == POISON) || (!own1 && a1 == POISON));
        if (!own0) bufn[w0] = __uint_as_float(a0);
        if (!own1) bufn[w1] = __uint_as_float(a1);
        __syncthreads();                         // single barrier per step
      }
    }
    return;
  }

  // ========================== loss: blocks 8..70 ==========================
  if (bx < 71) {
    const int t = bx - 8;
    // gate on init (U cells must be poisoned before we store real values)
    if (tid == 0) {
      while (__hip_atomic_load(flag_ready, __ATOMIC_ACQUIRE,
                               __HIP_MEMORY_SCOPE_AGENT) != MAGIC)
        __builtin_amdgcn_s_sleep(8);
    }
    __syncthreads();
    // ---- U[t] = hid_w[:, :300] @ cap0[t] + hid_b ----
    float* csh = smem;                     // 300
    if (tid < 256) csh[tid] = cap[t * 300 + tid];
    if (tid < 44) csh[256 + tid] = cap[t * 300 + 256 + tid];
    __syncthreads();
    #pragma unroll
    for (int rr = 0; rr < 2; ++rr) {
      int rrow = tid + rr * 256;
      float acc = hidb[rrow];
      const float4* w4 = (const float4*)(hidw + rrow * 812);
      const float4* c4 = (const float4*)csh;
      #pragma unroll 5
      for (int i = 0; i < 75; ++i) {
        float4 aa = w4[i]; float4 xx = c4[i];
        acc = fmaf(aa.x, xx.x, acc); acc = fmaf(aa.y, xx.y, acc);
        acc = fmaf(aa.z, xx.z, acc); acc = fmaf(aa.w, xx.w, acc);
      }
      fst(U + t * 512 + rrow, acc);
    }
    __syncthreads();
    // ---- wait for H row t: single-sentinel poll with backoff ----
    const unsigned* Hu = (const unsigned*)H;
    if (tid == 0) {
      while (uld(Hu + (size_t)t * 512) == POISON) __builtin_amdgcn_s_sleep(64);
    }
    __syncthreads();
    float* hsh = smem;                     // 512 (csh dead)
    {
      const unsigned* src = Hu + (size_t)t * 512;
      unsigned a0, a1;
      do {
        a0 = uld(src + tid);
        a1 = uld(src + tid + 256);
      } while (a0 == POISON || a1 == POISON);
      hsh[tid] = __uint_as_float(a0);
      hsh[tid + 256] = __uint_as_float(a1);
    }
    __syncthreads();
    float se = 0.f;
    #pragma unroll
    for (int rr = 0; rr < 2; ++rr) {
      int orow = tid + rr * 256;
      if (orow < 300) {
        float acc = outb[orow];
        const float4* w4 = (const float4*)(outw + orow * 512);
        const float4* h4 = (const float4*)hsh;
        #pragma unroll 4
        for (int i = 0; i < 128; ++i) {
          float4 aa = w4[i]; float4 xx = h4[i];
          acc = fmaf(aa.x, xx.x, acc); acc = fmaf(aa.y, xx.y, acc);
          acc = fmaf(aa.z, xx.z, acc); acc = fmaf(aa.w, xx.w, acc);
        }
        float y = sigmoidf_(acc);
        float d = y - cap[(t + 1) * 300 + orow];
        se = fmaf(d, d, se);
      }
    }
    #pragma unroll
    for (int o = 32; o > 0; o >>= 1) se += __shfl_down(se, o);
    float* red = smem + 512;
    if ((tid & 63) == 0) red[tid >> 6] = se;
    __syncthreads();
    if (tid == 0) {
      float tot = red[0] + red[1] + red[2] + red[3];
      atomicAdd(loss, tot * (1.0f / 19200.0f));
    }
    return;
  }

  // ========================== FC: blocks 71..78 ==========================
  if (bx < 79) {
    const int q = bx - 71;
    if (tid == 0) {
      while (uld(vlad_done) != 64u) __builtin_amdgcn_s_sleep(8);
    }
    __syncthreads();
    float* v  = smem;            // 1024
    float* rn = smem + 1024;     // 64
    float* fr = smem + 1088;     // 12
    for (int i = tid; i < 1024; i += 256)
      v[i] = fld(vacc + i) - fld(asum + (i >> 4)) * cent[i];
    __syncthreads();
    if (tid < 64) {
      float ss = 0.f;
      #pragma unroll
      for (int c = 0; c < 16; ++c) { float xx = v[tid * 16 + c]; ss = fmaf(xx, xx, ss); }
      rn[tid] = fmaxf(sqrtf(ss), 1e-12f);
    }
    __syncthreads();
    float gs = 0.f;
    for (int i = tid; i < 1024; i += 256) {
      float nv = v[i] / rn[i >> 4];
      v[i] = nv;
      gs = fmaf(nv, nv, gs);
    }
    #pragma unroll
    for (int o = 32; o > 0; o >>= 1) gs += __shfl_down(gs, o);
    if ((tid & 63) == 0) fr[tid >> 6] = gs;
    __syncthreads();
    if (tid == 0) {
      float tot = fr[0] + fr[1] + fr[2] + fr[3];
      fr[8] = 1.0f / fmaxf(sqrtf(tot), 1e-12f);
    }
    __syncthreads();
    float invg = fr[8];
    int row = q * 64 + (tid >> 2);
    int cg = tid & 3;
    float acc = 0.f;
    const float4* fw4 = (const float4*)(fcw + row * 1024 + cg * 256);
    const float4* v4  = (const float4*)(v + cg * 256);
    #pragma unroll 4
    for (int i = 0; i < 64; ++i) {
      float4 aa = fw4[i]; float4 xx = v4[i];
      acc = fmaf(aa.x, xx.x, acc); acc = fmaf(aa.y, xx.y, acc);
      acc = fmaf(aa.z, xx.z, acc); acc = fmaf(aa.w, xx.w, acc);
    }
    acc += __shfl_xor(acc, 1);
    acc += __shfl_xor(acc, 2);
    if (cg == 0) fst(feat + row, fmaf(invg, acc, fcb[row]));
    return;
  }

  // ===================== conv2+NetVLAD: blocks 79..142 =====================
  if (bx < 143) {
    const int vb = bx - 79;
    float* ps  = smem;           // 128*65 = 8320
    float* xs  = smem + 8320;    // 128*20 = 2560
    float* wsh = smem + 10880;   // 1024
    float* bsh = smem + 11904;   // 64
    float* aS  = smem + 11968;   // 256
    float* cw  = smem + 12224;   // 576
    float* cb  = smem + 12800;   // 16
    for (int i = tid; i < 1024; i += 256) wsh[i] = nvw[i];
    if (tid < 64) bsh[tid] = nvb[tid];
    for (int i = tid; i < 576; i += 256) cw[i] = c2w[i];
    if (tid < 16) cb[tid] = c2b[tid];
    if (tid == 0) {
      while (uld(conv_done) != 113u) __builtin_amdgcn_s_sleep(4);
    }
    __syncthreads();
    int ox = tid & 127;
    int oy = vb * 2 + (tid >> 7);
    int y0 = oy * 2 - 1, x0 = ox * 2 - 1;
    float a[16][4];
    #pragma unroll
    for (int oc = 0; oc < 16; ++oc) {
      float bb = cb[oc];
      a[oc][0] = bb; a[oc][1] = bb; a[oc][2] = bb; a[oc][3] = bb;
    }
    #pragma unroll
    for (int ci = 0; ci < 4; ++ci) {
      float P[4][4];
      #pragma unroll
      for (int j = 0; j < 4; ++j) {
        int y = y0 + j;
        #pragma unroll
        for (int i = 0; i < 4; ++i) {
          int x = x0 + i;
          bool ok = ((unsigned)y < 256u) && ((unsigned)x < 256u);
          P[j][i] = ok ? fld(p1 + ci * 65536 + y * 256 + x) : 0.0f;
        }
      }
      #pragma unroll
      for (int oc = 0; oc < 16; ++oc) {
        #pragma unroll
        for (int ky = 0; ky < 3; ++ky) {
          #pragma unroll
          for (int kx = 0; kx < 3; ++kx) {
            float wv = cw[oc * 36 + ci * 9 + ky * 3 + kx];
            a[oc][0] = fmaf(wv, P[ky][kx],         a[oc][0]);
            a[oc][1] = fmaf(wv, P[ky][kx + 1],     a[oc][1]);
            a[oc][2] = fmaf(wv, P[ky + 1][kx],     a[oc][2]);
            a[oc][3] = fmaf(wv, P[ky + 1][kx + 1], a[oc][3]);
          }
        }
      }
    }
    float x[16];
    #pragma unroll
    for (int oc = 0; oc < 16; ++oc)
      x[oc] = 0.25f * (fmaxf(a[oc][0], 0.f) + fmaxf(a[oc][1], 0.f) +
                       fmaxf(a[oc][2], 0.f) + fmaxf(a[oc][3], 0.f));
    float p[64];
    float m = -1e30f;
    #pragma unroll
    for (int k = 0; k < 64; ++k) {
      float acc = bsh[k];
      #pragma unroll
      for (int c = 0; c < 16; ++c) acc = fmaf(wsh[k * 16 + c], x[c], acc);
      p[k] = acc;
      m = fmaxf(m, acc);
    }
    float s = 0.f;
    #pragma unroll
    for (int k = 0; k < 64; ++k) { p[k] = __expf(p[k] - m); s += p[k]; }
    float inv = 1.0f / s;
    #pragma unroll
    for (int k = 0; k < 64; ++k) p[k] *= inv;

    int q = tid >> 6, k = tid & 63;
    float acc[16];
    #pragma unroll
    for (int c = 0; c < 16; ++c) acc[c] = 0.f;
    float accA = 0.f;
    for (int pass = 0; pass < 2; ++pass) {
      __syncthreads();
      if ((tid >> 7) == pass) {
        int tt = tid & 127;
        #pragma unroll
        for (int kk = 0; kk < 64; ++kk) ps[tt * 65 + kk] = p[kk];
        #pragma unroll
        for (int c = 0; c < 16; ++c) xs[tt * 20 + c] = x[c];
      }
      __syncthreads();
      #pragma unroll
      for (int j = 0; j < 32; ++j) {
        int tt = q * 32 + j;
        float pv = ps[tt * 65 + k];
        accA += pv;
        const float4* xv = (const float4*)(xs + tt * 20);
        #pragma unroll
        for (int c4 = 0; c4 < 4; ++c4) {
          float4 xx = xv[c4];
          acc[c4 * 4 + 0] = fmaf(pv, xx.x, acc[c4 * 4 + 0]);
          acc[c4 * 4 + 1] = fmaf(pv, xx.y, acc[c4 * 4 + 1]);
          acc[c4 * 4 + 2] = fmaf(pv, xx.z, acc[c4 * 4 + 2]);
          acc[c4 * 4 + 3] = fmaf(pv, xx.w, acc[c4 * 4 + 3]);
        }
      }
    }
    __syncthreads();
    float* red = ps;
    #pragma unroll
    for (int c = 0; c < 16; ++c) red[tid * 16 + c] = acc[c];
    aS[tid] = accA;
    __syncthreads();
    if (q == 0) {
      float aa = aS[k] + aS[64 + k] + aS[128 + k] + aS[192 + k];
      atomicAdd(&asum[k], aa);
    }
    int k2 = tid >> 2;
    int cgc = (tid & 3) * 4;
    #pragma unroll
    for (int cc = 0; cc < 4; ++cc) {
      int c = cgc + cc;
      float vv = red[(0 * 64 + k2) * 16 + c] + red[(1 * 64 + k2) * 16 + c] +
                 red[(2 * 64 + k2) * 16 + c] + red[(3 * 64 + k2) * 16 + c];
      atomicAdd(&vacc[k2 * 16 + c], vv);
    }
    __syncthreads();   // drain atomics before tick
    if (tid == 0)
      __hip_atomic_fetch_add(vlad_done, 1u, __ATOMIC_RELAXED,
                             __HIP_MEMORY_SCOPE_AGENT);
    return;
  }

  // ======================== conv1: blocks 143..255 ========================
  {
    const int cbk = bx - 143;               // 0..112
    float* cwsh = smem;                     // 108 w + 4 b
    if (tid < 108) cwsh[tid] = c1w[tid];
    if (tid < 4) cwsh[108 + tid] = c1b[tid];
    __syncthreads();
    for (int o = cbk * 256 + tid; o < 262144; o += 113 * 256) {
      int c  = o >> 16;
      int oy = (o >> 8) & 255;
      int ox = o & 255;
      int y0 = oy * 2 - 1, x0 = ox * 2 - 1;
      float a00, a01, a10, a11;
      a00 = a01 = a10 = a11 = cwsh[108 + c];
      #pragma unroll
      for (int ci = 0; ci < 3; ++ci) {
        float P[4][4];
        #pragma unroll
        for (int j = 0; j < 4; ++j) {
          int y = y0 + j;
          #pragma unroll
          for (int i = 0; i < 4; ++i) {
            int x = x0 + i;
            bool ok = ((unsigned)y < 512u) && ((unsigned)x < 512u);
            P[j][i] = ok ? img[ci * 262144 + y * 512 + x] : 0.0f;
          }
        }
        #pragma unroll
        for (int ky = 0; ky < 3; ++ky) {
          #pragma unroll
          for (int kx = 0; kx < 3; ++kx) {
            float wv = cwsh[c * 27 + ci * 9 + ky * 3 + kx];
            a00 = fmaf(wv, P[ky][kx],         a00);
            a01 = fmaf(wv, P[ky][kx + 1],     a01);
            a10 = fmaf(wv, P[ky + 1][kx],     a10);
            a11 = fmaf(wv, P[ky + 1][kx + 1], a11);
          }
        }
      }
      fst(p1 + o, 0.25f * (fmaxf(a00, 0.f) + fmaxf(a01, 0.f) +
                           fmaxf(a10, 0.f) + fmaxf(a11, 0.f)));
    }
    __syncthreads();   // drain p1 stores for all waves
    if (tid == 0) {
      while (__hip_atomic_load(flag_ready, __ATOMIC_ACQUIRE,
                               __HIP_MEMORY_SCOPE_AGENT) != MAGIC)
        __builtin_amdgcn_s_sleep(2);
      __hip_atomic_fetch_add(conv_done, 1u, __ATOMIC_RELAXED,
                             __HIP_MEMORY_SCOPE_AGENT);
    }
  }
}

extern "C" void kernel_launch(void* const* d_in, const int* in_sizes, int n_in,
                              void* d_out, int out_size, void* d_ws, size_t ws_size,
                              hipStream_t stream) {
  (void)in_sizes; (void)n_in; (void)out_size; (void)ws_size;
  const float* img  = (const float*)d_in[0];   // sample 0 only
  const float* cap  = (const float*)d_in[1];   // sample 0 only
  const float* c1w  = (const float*)d_in[2];
  const float* c1b  = (const float*)d_in[3];
  const float* c2w  = (const float*)d_in[4];
  const float* c2b  = (const float*)d_in[5];
  const float* cent = (const float*)d_in[6];
  const float* nvw  = (const float*)d_in[7];
  const float* nvb  = (const float*)d_in[8];
  const float* fcw  = (const float*)d_in[9];
  const float* fcb  = (const float*)d_in[10];
  const float* hidw = (const float*)d_in[11];
  const float* hidb = (const float*)d_in[12];
  const float* outw = (const float*)d_in[13];
  const float* outb = (const float*)d_in[14];

  float* ws   = (float*)d_ws;
  float* p1   = ws;                   // 262144
  float* vacc = ws + 262144;          // 1024
  float* asum = ws + 263168;          // 64
  float* feat = ws + 263232;          // 512
  float* U    = ws + 263744;          // 63*512 = 32256
  float* H    = ws + 296000;          // 63*512 = 32256
  unsigned* flags = (unsigned*)(ws + 328256);  // [ready, conv_done, vlad_done]

  k_fused<<<256, 256, 0, stream>>>(img, cap, c1w, c1b, c2w, c2b, cent, nvw,
                                   nvb, fcw, fcb, hidw, hidb, outw, outb,
                                   p1, vacc, asum, feat, U, H, flags,
                                   (float*)d_out);
}

// Round 6
// 291.997 us; speedup vs baseline: 1.0048x; 1.0048x over previous
//
#include <hip/hip_runtime.h>
#include <math.h>

// ---------------------------------------------------------------------------
// Only sample 0 of the batch affects the loss (features[0], cap[0]).
// Two kernels (isolation of front vs recurrence):
//  K1 k_front (grid 256 = 1 block/CU, role-partitioned, relaxed-only flags):
//     bx 0..62    U[t] = hid_w[:, :300] @ cap0[t] + hid_b  (plain stores)
//     bx 63..70   FC: wait vlad_done==64, normalize vlad, 64 feat rows each
//     bx 71..134  conv2+relu+pool fused with NetVLAD softmax+accumulate;
//                 wait conv_done==121 (relaxed); tick vlad_done
//     bx 135..255 conv1+relu+pool -> p1 (uncached stores); bx 255 does init
//                 (zero vacc/asum/flags/loss, poison H 0xAA) then MAGIC;
//                 every conv1 block ticks conv_done after MAGIC is seen.
//  K2 k_back (grid 71): bx 0..7 = RNN (64 rows/block, W_h in VGPRs,
//     DATA-AS-FLAG: H pre-poisoned 0xAA, sigmoid outputs can't be 0xAA..;
//     one concurrent 2-cell poll + single barrier per step; U/feat are plain
//     cached loads thanks to the kernel boundary). bx 8..70 = loss row t:
//     sentinel poll with s_sleep backoff, then y_t/squared error -> loss.
// ---------------------------------------------------------------------------

#define POISON 0xAAAAAAAAu
#define MAGIC  0x13579BDFu

__device__ __forceinline__ float sigmoidf_(float x) {
  return 1.0f / (1.0f + __expf(-x));
}
__device__ __forceinline__ unsigned uld(const unsigned* p) {
  return __hip_atomic_load(p, __ATOMIC_RELAXED, __HIP_MEMORY_SCOPE_AGENT);
}
__device__ __forceinline__ float fld(const float* p) {
  return __hip_atomic_load(p, __ATOMIC_RELAXED, __HIP_MEMORY_SCOPE_AGENT);
}
__device__ __forceinline__ void fst(float* p, float v) {
  __hip_atomic_store(p, v, __ATOMIC_RELAXED, __HIP_MEMORY_SCOPE_AGENT);
}
__device__ __forceinline__ void ust(unsigned* p, unsigned v) {
  __hip_atomic_store(p, v, __ATOMIC_RELAXED, __HIP_MEMORY_SCOPE_AGENT);
}

// ============================ K1: front ============================
__global__ __launch_bounds__(256, 1)
void k_front(const float* __restrict__ img,  const float* __restrict__ cap,
             const float* __restrict__ c1w,  const float* __restrict__ c1b,
             const float* __restrict__ c2w,  const float* __restrict__ c2b,
             const float* __restrict__ cent, const float* __restrict__ nvw,
             const float* __restrict__ nvb,  const float* __restrict__ fcw,
             const float* __restrict__ fcb,  const float* __restrict__ hidw,
             const float* __restrict__ hidb,
             float* __restrict__ p1,   float* __restrict__ vacc,
             float* __restrict__ asum, float* __restrict__ feat,
             float* __restrict__ U,    float* __restrict__ H,
             unsigned* __restrict__ flags, float* __restrict__ loss) {
  __shared__ __align__(16) float smem[12832];
  const int bx  = blockIdx.x;
  const int tid = threadIdx.x;
  unsigned* flag_magic = flags + 0;
  unsigned* conv_done  = flags + 1;
  unsigned* vlad_done  = flags + 2;

  // -------------------- U blocks: 0..62 --------------------
  if (bx < 63) {
    const int t = bx;
    float* csh = smem;                     // 300
    if (tid < 256) csh[tid] = cap[t * 300 + tid];
    if (tid < 44) csh[256 + tid] = cap[t * 300 + 256 + tid];
    __syncthreads();
    #pragma unroll
    for (int rr = 0; rr < 2; ++rr) {
      int row = tid + rr * 256;
      float acc = hidb[row];
      const float4* w4 = (const float4*)(hidw + row * 812);
      const float4* c4 = (const float4*)csh;
      #pragma unroll 5
      for (int i = 0; i < 75; ++i) {
        float4 aa = w4[i]; float4 xx = c4[i];
        acc = fmaf(aa.x, xx.x, acc); acc = fmaf(aa.y, xx.y, acc);
        acc = fmaf(aa.z, xx.z, acc); acc = fmaf(aa.w, xx.w, acc);
      }
      U[t * 512 + row] = acc;              // plain store: K2 is a new kernel
    }
    return;
  }

  // -------------------- FC blocks: 63..70 --------------------
  if (bx < 71) {
    const int q = bx - 63;
    if (tid == 0) {
      while (uld(vlad_done) != 64u) __builtin_amdgcn_s_sleep(8);
    }
    __syncthreads();
    float* v  = smem;            // 1024
    float* rn = smem + 1024;     // 64
    float* fr = smem + 1088;     // 12
    for (int i = tid; i < 1024; i += 256)
      v[i] = fld(vacc + i) - fld(asum + (i >> 4)) * cent[i];
    __syncthreads();
    if (tid < 64) {
      float ss = 0.f;
      #pragma unroll
      for (int c = 0; c < 16; ++c) { float xx = v[tid * 16 + c]; ss = fmaf(xx, xx, ss); }
      rn[tid] = fmaxf(sqrtf(ss), 1e-12f);
    }
    __syncthreads();
    float gs = 0.f;
    for (int i = tid; i < 1024; i += 256) {
      float nv = v[i] / rn[i >> 4];
      v[i] = nv;
      gs = fmaf(nv, nv, gs);
    }
    #pragma unroll
    for (int o = 32; o > 0; o >>= 1) gs += __shfl_down(gs, o);
    if ((tid & 63) == 0) fr[tid >> 6] = gs;
    __syncthreads();
    if (tid == 0) {
      float tot = fr[0] + fr[1] + fr[2] + fr[3];
      fr[8] = 1.0f / fmaxf(sqrtf(tot), 1e-12f);
    }
    __syncthreads();
    float invg = fr[8];
    int row = q * 64 + (tid >> 2);
    int cg = tid & 3;
    float acc = 0.f;
    const float4* fw4 = (const float4*)(fcw + row * 1024 + cg * 256);
    const float4* v4  = (const float4*)(v + cg * 256);
    #pragma unroll 4
    for (int i = 0; i < 64; ++i) {
      float4 aa = fw4[i]; float4 xx = v4[i];
      acc = fmaf(aa.x, xx.x, acc); acc = fmaf(aa.y, xx.y, acc);
      acc = fmaf(aa.z, xx.z, acc); acc = fmaf(aa.w, xx.w, acc);
    }
    acc += __shfl_xor(acc, 1);
    acc += __shfl_xor(acc, 2);
    if (cg == 0) feat[row] = fmaf(invg, acc, fcb[row]);   // plain store
    return;
  }

  // -------------------- conv2+NetVLAD blocks: 71..134 --------------------
  if (bx < 135) {
    const int vb = bx - 71;
    float* ps  = smem;           // 128*65 = 8320
    float* xs  = smem + 8320;    // 128*20 = 2560
    float* wsh = smem + 10880;   // 1024
    float* bsh = smem + 11904;   // 64
    float* aS  = smem + 11968;   // 256
    float* cw  = smem + 12224;   // 576
    float* cb  = smem + 12800;   // 16
    for (int i = tid; i < 1024; i += 256) wsh[i] = nvw[i];
    if (tid < 64) bsh[tid] = nvb[tid];
    for (int i = tid; i < 576; i += 256) cw[i] = c2w[i];
    if (tid < 16) cb[tid] = c2b[tid];
    if (tid == 0) {
      while (uld(conv_done) != 121u) __builtin_amdgcn_s_sleep(4);
    }
    __syncthreads();
    int ox = tid & 127;
    int oy = vb * 2 + (tid >> 7);
    int y0 = oy * 2 - 1, x0 = ox * 2 - 1;
    float a[16][4];
    #pragma unroll
    for (int oc = 0; oc < 16; ++oc) {
      float bb = cb[oc];
      a[oc][0] = bb; a[oc][1] = bb; a[oc][2] = bb; a[oc][3] = bb;
    }
    #pragma unroll
    for (int ci = 0; ci < 4; ++ci) {
      float P[4][4];
      #pragma unroll
      for (int j = 0; j < 4; ++j) {
        int y = y0 + j;
        #pragma unroll
        for (int i = 0; i < 4; ++i) {
          int x = x0 + i;
          bool ok = ((unsigned)y < 256u) && ((unsigned)x < 256u);
          P[j][i] = ok ? fld(p1 + ci * 65536 + y * 256 + x) : 0.0f;
        }
      }
      #pragma unroll
      for (int oc = 0; oc < 16; ++oc) {
        #pragma unroll
        for (int ky = 0; ky < 3; ++ky) {
          #pragma unroll
          for (int kx = 0; kx < 3; ++kx) {
            float wv = cw[oc * 36 + ci * 9 + ky * 3 + kx];
            a[oc][0] = fmaf(wv, P[ky][kx],         a[oc][0]);
            a[oc][1] = fmaf(wv, P[ky][kx + 1],     a[oc][1]);
            a[oc][2] = fmaf(wv, P[ky + 1][kx],     a[oc][2]);
            a[oc][3] = fmaf(wv, P[ky + 1][kx + 1], a[oc][3]);
          }
        }
      }
    }
    float x[16];
    #pragma unroll
    for (int oc = 0; oc < 16; ++oc)
      x[oc] = 0.25f * (fmaxf(a[oc][0], 0.f) + fmaxf(a[oc][1], 0.f) +
                       fmaxf(a[oc][2], 0.f) + fmaxf(a[oc][3], 0.f));
    float p[64];
    float m = -1e30f;
    #pragma unroll
    for (int k = 0; k < 64; ++k) {
      float acc = bsh[k];
      #pragma unroll
      for (int c = 0; c < 16; ++c) acc = fmaf(wsh[k * 16 + c], x[c], acc);
      p[k] = acc;
      m = fmaxf(m, acc);
    }
    float s = 0.f;
    #pragma unroll
    for (int k = 0; k < 64; ++k) { p[k] = __expf(p[k] - m); s += p[k]; }
    float inv = 1.0f / s;
    #pragma unroll
    for (int k = 0; k < 64; ++k) p[k] *= inv;

    int q = tid >> 6, k = tid & 63;
    float acc[16];
    #pragma unroll
    for (int c = 0; c < 16; ++c) acc[c] = 0.f;
    float accA = 0.f;
    for (int pass = 0; pass < 2; ++pass) {
      __syncthreads();
      if ((tid >> 7) == pass) {
        int tt = tid & 127;
        #pragma unroll
        for (int kk = 0; kk < 64; ++kk) ps[tt * 65 + kk] = p[kk];
        #pragma unroll
        for (int c = 0; c < 16; ++c) xs[tt * 20 + c] = x[c];
      }
      __syncthreads();
      #pragma unroll
      for (int j = 0; j < 32; ++j) {
        int tt = q * 32 + j;
        float pv = ps[tt * 65 + k];
        accA += pv;
        const float4* xv = (const float4*)(xs + tt * 20);
        #pragma unroll
        for (int c4 = 0; c4 < 4; ++c4) {
          float4 xx = xv[c4];
          acc[c4 * 4 + 0] = fmaf(pv, xx.x, acc[c4 * 4 + 0]);
          acc[c4 * 4 + 1] = fmaf(pv, xx.y, acc[c4 * 4 + 1]);
          acc[c4 * 4 + 2] = fmaf(pv, xx.z, acc[c4 * 4 + 2]);
          acc[c4 * 4 + 3] = fmaf(pv, xx.w, acc[c4 * 4 + 3]);
        }
      }
    }
    __syncthreads();
    float* red = ps;
    #pragma unroll
    for (int c = 0; c < 16; ++c) red[tid * 16 + c] = acc[c];
    aS[tid] = accA;
    __syncthreads();
    if (q == 0) {
      float aa = aS[k] + aS[64 + k] + aS[128 + k] + aS[192 + k];
      atomicAdd(&asum[k], aa);
    }
    int k2 = tid >> 2;
    int cgc = (tid & 3) * 4;
    #pragma unroll
    for (int cc = 0; cc < 4; ++cc) {
      int c = cgc + cc;
      float vv = red[(0 * 64 + k2) * 16 + c] + red[(1 * 64 + k2) * 16 + c] +
                 red[(2 * 64 + k2) * 16 + c] + red[(3 * 64 + k2) * 16 + c];
      atomicAdd(&vacc[k2 * 16 + c], vv);
    }
    __syncthreads();   // drain atomics before tick
    if (tid == 0)
      __hip_atomic_fetch_add(vlad_done, 1u, __ATOMIC_RELAXED,
                             __HIP_MEMORY_SCOPE_AGENT);
    return;
  }

  // -------------------- conv1 blocks: 135..255 --------------------
  {
    const int cbk = bx - 135;               // 0..120
    if (cbk == 120) {
      // ---- init: zero accumulators/flags/loss, poison H ----
      for (int i = tid; i < 1024; i += 256) fst(vacc + i, 0.f);
      if (tid < 64) fst(asum + tid, 0.f);
      if (tid == 0) { fst(loss, 0.f); ust(conv_done, 0u); ust(vlad_done, 0u); }
      unsigned* Hu = (unsigned*)H;
      for (int i = tid; i < 63 * 512; i += 256) ust(Hu + i, POISON);
      __syncthreads();                      // drains vmcnt -> stores visible
      if (tid == 0) ust(flag_magic, MAGIC);
    }
    float* cwsh = smem;                     // 108 w + 4 b
    if (tid < 108) cwsh[tid] = c1w[tid];
    if (tid < 4) cwsh[108 + tid] = c1b[tid];
    __syncthreads();
    for (int o = cbk * 256 + tid; o < 262144; o += 121 * 256) {
      int c  = o >> 16;
      int oy = (o >> 8) & 255;
      int ox = o & 255;
      int y0 = oy * 2 - 1, x0 = ox * 2 - 1;
      float a00, a01, a10, a11;
      a00 = a01 = a10 = a11 = cwsh[108 + c];
      #pragma unroll
      for (int ci = 0; ci < 3; ++ci) {
        float P[4][4];
        #pragma unroll
        for (int j = 0; j < 4; ++j) {
          int y = y0 + j;
          #pragma unroll
          for (int i = 0; i < 4; ++i) {
            int x = x0 + i;
            bool ok = ((unsigned)y < 512u) && ((unsigned)x < 512u);
            P[j][i] = ok ? img[ci * 262144 + y * 512 + x] : 0.0f;
          }
        }
        #pragma unroll
        for (int ky = 0; ky < 3; ++ky) {
          #pragma unroll
          for (int kx = 0; kx < 3; ++kx) {
            float wv = cwsh[c * 27 + ci * 9 + ky * 3 + kx];
            a00 = fmaf(wv, P[ky][kx],         a00);
            a01 = fmaf(wv, P[ky][kx + 1],     a01);
            a10 = fmaf(wv, P[ky + 1][kx],     a10);
            a11 = fmaf(wv, P[ky + 1][kx + 1], a11);
          }
        }
      }
      fst(p1 + o, 0.25f * (fmaxf(a00, 0.f) + fmaxf(a01, 0.f) +
                           fmaxf(a10, 0.f) + fmaxf(a11, 0.f)));
    }
    __syncthreads();   // drain p1 stores for all waves
    if (tid == 0) {
      while (uld(flag_magic) != MAGIC) __builtin_amdgcn_s_sleep(2);
      __hip_atomic_fetch_add(conv_done, 1u, __ATOMIC_RELAXED,
                             __HIP_MEMORY_SCOPE_AGENT);
    }
  }
}

// ============================ K2: RNN + loss ============================
__global__ __launch_bounds__(256, 1)
void k_back(const float* __restrict__ hidw, const float* __restrict__ U,
            const float* __restrict__ feat, float* __restrict__ H,
            const float* __restrict__ outw, const float* __restrict__ outb,
            const float* __restrict__ cap,  float* __restrict__ loss) {
  __shared__ __align__(16) float smem[1100];
  const int bx  = blockIdx.x;
  const int tid = threadIdx.x;
  unsigned* Hu = (unsigned*)H;

  if (bx < 8) {
    // -------- RNN: 64 rows/block, W_h in VGPRs, data-as-flag sync --------
    const int r   = tid >> 2;
    const int cg  = tid & 3;
    const int row = bx * 64 + r;
    float4 wr[32];
    const float4* wp = (const float4*)(hidw + row * 812 + 300 + cg * 128);
    #pragma unroll
    for (int i = 0; i < 32; ++i) wr[i] = wp[i];
    float* buf0 = smem;          // 544 floats, swizzled (chunk k at k*136)
    float* buf1 = smem + 544;
    const int w0 = (tid >> 7) * 136 + (tid & 127);
    const int w1 = ((tid + 256) >> 7) * 136 + ((tid + 256) & 127);
    const int wown = (row >> 7) * 136 + (row & 127);
    const bool own0 = ((tid >> 6) == bx);
    const bool own1 = (((tid + 256) >> 6) == bx);
    buf0[w0] = feat[tid];                  // plain cached loads (K1 done)
    buf0[w1] = feat[tid + 256];
    __syncthreads();
    for (int t = 0; t < 63; ++t) {
      const float* bufc = (t & 1) ? buf1 : buf0;
      const float* rb = bufc + cg * 136;
      float uval = (cg == 0) ? U[t * 512 + row] : 0.f;   // cached load
      float acc = 0.f;
      #pragma unroll
      for (int i = 0; i < 32; ++i) {
        float4 h4 = *(const float4*)(rb + i * 4);
        acc = fmaf(wr[i].x, h4.x, acc);
        acc = fmaf(wr[i].y, h4.y, acc);
        acc = fmaf(wr[i].z, h4.z, acc);
        acc = fmaf(wr[i].w, h4.w, acc);
      }
      acc += __shfl_xor(acc, 1);
      acc += __shfl_xor(acc, 2);
      float hn = 0.f;
      if (cg == 0) {
        hn = sigmoidf_(acc + uval);
        fst(H + t * 512 + row, hn);
      }
      if (t < 62) {
        float* bufn = (t & 1) ? buf0 : buf1;
        if (cg == 0) bufn[wown] = hn;      // own row via LDS, no global RT
        const unsigned* src = Hu + t * 512;
        unsigned a0 = 0, a1 = 0;
        do {                               // both polls in flight together
          if (!own0) a0 = uld(src + tid);
          if (!own1) a1 = uld(src + tid + 256);
        } while ((!own0 && a0 == POISON) || (!own1 && a1 == POISON));
        if (!own0) bufn[w0] = __uint_as_float(a0);
        if (!own1) bufn[w1] = __uint_as_float(a1);
        __syncthreads();                   // single barrier per step
      }
    }
    return;
  }

  // -------- loss block for timestep t --------
  const int t = bx - 8;
  float* hsh = smem;                       // 512
  float* red = smem + 512;                 // 4
  if (tid == 0) {
    while (uld(Hu + (size_t)t * 512) == POISON) __builtin_amdgcn_s_sleep(64);
  }
  __syncthreads();
  {
    const unsigned* src = Hu + (size_t)t * 512;
    unsigned a0, a1;
    do {
      a0 = uld(src + tid);
      a1 = uld(src + tid + 256);
    } while (a0 == POISON || a1 == POISON);
    hsh[tid] = __uint_as_float(a0);
    hsh[tid + 256] = __uint_as_float(a1);
  }
  __syncthreads();
  float se = 0.f;
  #pragma unroll
  for (int rr = 0; rr < 2; ++rr) {
    int orow = tid + rr * 256;
    if (orow < 300) {
      float acc = outb[orow];
      const float4* w4 = (const float4*)(outw + orow * 512);
      const float4* h4 = (const float4*)hsh;
      #pragma unroll 4
      for (int i = 0; i < 128; ++i) {
        float4 aa = w4[i]; float4 xx = h4[i];
        acc = fmaf(aa.x, xx.x, acc); acc = fmaf(aa.y, xx.y, acc);
        acc = fmaf(aa.z, xx.z, acc); acc = fmaf(aa.w, xx.w, acc);
      }
      float y = sigmoidf_(acc);
      float d = y - cap[(t + 1) * 300 + orow];
      se = fmaf(d, d, se);
    }
  }
  #pragma unroll
  for (int o = 32; o > 0; o >>= 1) se += __shfl_down(se, o);
  if ((tid & 63) == 0) red[tid >> 6] = se;
  __syncthreads();
  if (tid == 0) {
    float tot = red[0] + red[1] + red[2] + red[3];
    atomicAdd(loss, tot * (1.0f / 19200.0f));
  }
}

extern "C" void kernel_launch(void* const* d_in, const int* in_sizes, int n_in,
                              void* d_out, int out_size, void* d_ws, size_t ws_size,
                              hipStream_t stream) {
  (void)in_sizes; (void)n_in; (void)out_size; (void)ws_size;
  const float* img  = (const float*)d_in[0];   // sample 0 only
  const float* cap  = (const float*)d_in[1];   // sample 0 only
  const float* c1w  = (const float*)d_in[2];
  const float* c1b  = (const float*)d_in[3];
  const float* c2w  = (const float*)d_in[4];
  const float* c2b  = (const float*)d_in[5];
  const float* cent = (const float*)d_in[6];
  const float* nvw  = (const float*)d_in[7];
  const float* nvb  = (const float*)d_in[8];
  const float* fcw  = (const float*)d_in[9];
  const float* fcb  = (const float*)d_in[10];
  const float* hidw = (const float*)d_in[11];
  const float* hidb = (const float*)d_in[12];
  const float* outw = (const float*)d_in[13];
  const float* outb = (const float*)d_in[14];

  float* ws   = (float*)d_ws;
  float* p1   = ws;                   // 262144
  float* vacc = ws + 262144;          // 1024
  float* asum = ws + 263168;          // 64
  float* feat = ws + 263232;          // 512
  float* U    = ws + 263744;          // 63*512 = 32256
  float* H    = ws + 296000;          // 63*512 = 32256
  unsigned* flags = (unsigned*)(ws + 328256);  // [magic, conv_done, vlad_done]

  k_front<<<256, 256, 0, stream>>>(img, cap, c1w, c1b, c2w, c2b, cent, nvw,
                                   nvb, fcw, fcb, hidw, hidb,
                                   p1, vacc, asum, feat, U, H, flags,
                                   (float*)d_out);
  k_back<<<71, 256, 0, stream>>>(hidw, U, feat, H, outw, outb, cap,
                                 (float*)d_out);
}

// Round 7
// 287.788 us; speedup vs baseline: 1.0195x; 1.0146x over previous
//
#include <hip/hip_runtime.h>
#include <math.h>

// ---------------------------------------------------------------------------
// Only sample 0 of the batch affects the loss (features[0], cap[0]).
// K1 k_front grid 136x256:
//   bx 0       init: zero vacc/asum/vlad_done/loss (agent stores), poison H
//              with 0xAA (agent stores), then release MAGIC.
//   bx 1..63   U[t] = hid_w[:, :300] @ cap0[t] + hid_b (plain stores; K2 is
//              a separate kernel so plain cached loads see them).
//   bx 64..71  FC: wait vlad_done==64, normalize vlad, 64 feat rows each.
//   bx 72..135 conv1+conv2+NetVLAD fully fused: conv1+pool computed into an
//              LDS p1 tile (4ch x 6 x 258, halo zeroed; ~1.5x redundant
//              conv1 work, img reads cached) -> conv2+relu+pool -> softmax
//              -> accumulate. MAGIC gate only before the vacc/asum atomics.
// K2 k_back grid 67x512:
//   bx 0..3    RNN, 128 rows/block. W_h slice held in VGPRs, enforced with
//              an opaque asm pin (compiler can't rematerialize -> no per-step
//              L2 re-stream; R6's VGPR_Count=80 proved wr[] was re-loaded).
//              DATA-AS-FLAG sync on H (pre-poisoned 0xAA; sigmoid outputs
//              can never be 0xAA..): 1 cell polled/thread, double-buffered
//              swizzled LDS, single barrier per step.
//   bx 4..66   loss row t: sentinel poll + row poll, y_t, squared error.
// ---------------------------------------------------------------------------

#define POISON 0xAAAAAAAAu
#define MAGIC  0x13579BDFu

__device__ __forceinline__ float sigmoidf_(float x) {
  return 1.0f / (1.0f + __expf(-x));
}
__device__ __forceinline__ unsigned uld(const unsigned* p) {
  return __hip_atomic_load(p, __ATOMIC_RELAXED, __HIP_MEMORY_SCOPE_AGENT);
}
__device__ __forceinline__ float fld(const float* p) {
  return __hip_atomic_load(p, __ATOMIC_RELAXED, __HIP_MEMORY_SCOPE_AGENT);
}
__device__ __forceinline__ void fst(float* p, float v) {
  __hip_atomic_store(p, v, __ATOMIC_RELAXED, __HIP_MEMORY_SCOPE_AGENT);
}
__device__ __forceinline__ void ust(unsigned* p, unsigned v) {
  __hip_atomic_store(p, v, __ATOMIC_RELAXED, __HIP_MEMORY_SCOPE_AGENT);
}

// ============================ K1: front ============================
__global__ __launch_bounds__(256, 1)
void k_front(const float* __restrict__ img,  const float* __restrict__ cap,
             const float* __restrict__ c1w,  const float* __restrict__ c1b,
             const float* __restrict__ c2w,  const float* __restrict__ c2b,
             const float* __restrict__ cent, const float* __restrict__ nvw,
             const float* __restrict__ nvb,  const float* __restrict__ fcw,
             const float* __restrict__ fcb,  const float* __restrict__ hidw,
             const float* __restrict__ hidb,
             float* __restrict__ vacc, float* __restrict__ asum,
             float* __restrict__ feat, float* __restrict__ U,
             float* __restrict__ H,
             unsigned* __restrict__ flags, float* __restrict__ loss) {
  __shared__ __align__(16) float smem[19392];
  const int bx  = blockIdx.x;
  const int tid = threadIdx.x;
  unsigned* flag_magic = flags + 0;
  unsigned* vlad_done  = flags + 1;

  // -------------------- init block: bx 0 --------------------
  if (bx == 0) {
    for (int i = tid; i < 1024; i += 256) fst(vacc + i, 0.f);
    if (tid < 64) fst(asum + tid, 0.f);
    if (tid == 0) { fst(loss, 0.f); ust(vlad_done, 0u); }
    unsigned* Hu = (unsigned*)H;
    for (int i = tid; i < 63 * 512; i += 256) ust(Hu + i, POISON);
    __syncthreads();                      // drain stores before MAGIC
    if (tid == 0) ust(flag_magic, MAGIC);
    return;
  }

  // -------------------- U blocks: 1..63 --------------------
  if (bx < 64) {
    const int t = bx - 1;
    float* csh = smem;                     // 300
    if (tid < 256) csh[tid] = cap[t * 300 + tid];
    if (tid < 44) csh[256 + tid] = cap[t * 300 + 256 + tid];
    __syncthreads();
    #pragma unroll
    for (int rr = 0; rr < 2; ++rr) {
      int row = tid + rr * 256;
      float acc = hidb[row];
      const float4* w4 = (const float4*)(hidw + row * 812);
      const float4* c4 = (const float4*)csh;
      #pragma unroll 5
      for (int i = 0; i < 75; ++i) {
        float4 aa = w4[i]; float4 xx = c4[i];
        acc = fmaf(aa.x, xx.x, acc); acc = fmaf(aa.y, xx.y, acc);
        acc = fmaf(aa.z, xx.z, acc); acc = fmaf(aa.w, xx.w, acc);
      }
      U[t * 512 + row] = acc;              // plain store: K2 is a new kernel
    }
    return;
  }

  // -------------------- FC blocks: 64..71 --------------------
  if (bx < 72) {
    const int q = bx - 64;
    if (tid == 0) {
      while (uld(vlad_done) != 64u) __builtin_amdgcn_s_sleep(8);
    }
    __syncthreads();
    float* v  = smem;            // 1024
    float* rn = smem + 1024;     // 64
    float* fr = smem + 1088;     // 12
    for (int i = tid; i < 1024; i += 256)
      v[i] = fld(vacc + i) - fld(asum + (i >> 4)) * cent[i];
    __syncthreads();
    if (tid < 64) {
      float ss = 0.f;
      #pragma unroll
      for (int c = 0; c < 16; ++c) { float xx = v[tid * 16 + c]; ss = fmaf(xx, xx, ss); }
      rn[tid] = fmaxf(sqrtf(ss), 1e-12f);
    }
    __syncthreads();
    float gs = 0.f;
    for (int i = tid; i < 1024; i += 256) {
      float nv = v[i] / rn[i >> 4];
      v[i] = nv;
      gs = fmaf(nv, nv, gs);
    }
    #pragma unroll
    for (int o = 32; o > 0; o >>= 1) gs += __shfl_down(gs, o);
    if ((tid & 63) == 0) fr[tid >> 6] = gs;
    __syncthreads();
    if (tid == 0) {
      float tot = fr[0] + fr[1] + fr[2] + fr[3];
      fr[8] = 1.0f / fmaxf(sqrtf(tot), 1e-12f);
    }
    __syncthreads();
    float invg = fr[8];
    int row = q * 64 + (tid >> 2);
    int cg = tid & 3;
    float acc = 0.f;
    const float4* fw4 = (const float4*)(fcw + row * 1024 + cg * 256);
    const float4* v4  = (const float4*)(v + cg * 256);
    #pragma unroll 4
    for (int i = 0; i < 64; ++i) {
      float4 aa = fw4[i]; float4 xx = v4[i];
      acc = fmaf(aa.x, xx.x, acc); acc = fmaf(aa.y, xx.y, acc);
      acc = fmaf(aa.z, xx.z, acc); acc = fmaf(aa.w, xx.w, acc);
    }
    acc += __shfl_xor(acc, 1);
    acc += __shfl_xor(acc, 2);
    if (cg == 0) feat[row] = fmaf(invg, acc, fcb[row]);   // plain store
    return;
  }

  // ------------- conv1+conv2+NetVLAD blocks: 72..135 -------------
  {
    const int vb = bx - 72;                // 0..63
    float* p1sh = smem;                    // 4*6*264 = 6336
    float* ps   = smem + 6336;             // 128*65 = 8320
    float* xs   = smem + 14656;            // 128*20 = 2560
    float* wsh  = smem + 17216;            // 1024
    float* bsh  = smem + 18240;            // 64
    float* aS   = smem + 18304;            // 256
    float* cw2  = smem + 18560;            // 576
    float* cb2  = smem + 19136;            // 16
    float* cw1  = smem + 19152;            // 108
    float* cb1  = smem + 19260;            // 4
    for (int i = tid; i < 1024; i += 256) wsh[i] = nvw[i];
    if (tid < 64) bsh[tid] = nvb[tid];
    for (int i = tid; i < 576; i += 256) cw2[i] = c2w[i];
    if (tid < 16) cb2[tid] = c2b[tid];
    if (tid < 108) cw1[tid] = c1w[tid];
    if (tid >= 108 && tid < 112) cb1[tid - 108] = c1b[tid - 108];
    __syncthreads();

    // ---- conv1 + relu + pool into LDS p1 tile ----
    // tile: channels 4, p1 rows [4vb-1, 4vb+4] (6), p1 cols [-1, 256] (258)
    for (int f = tid; f < 6192; f += 256) {
      int c  = f / 1548;
      int r0 = f - c * 1548;
      int j  = r0 / 258;
      int xx = r0 - j * 258;
      int gy = 4 * vb - 1 + j;
      int gx = xx - 1;
      float val = 0.f;
      if ((unsigned)gy < 256u && (unsigned)gx < 256u) {
        float bb = cb1[c];
        float a00 = bb, a01 = bb, a10 = bb, a11 = bb;
        int y0 = 2 * gy - 1, x0 = 2 * gx - 1;
        #pragma unroll
        for (int ci = 0; ci < 3; ++ci) {
          float P[4][4];
          #pragma unroll
          for (int jj = 0; jj < 4; ++jj) {
            int y = y0 + jj;
            #pragma unroll
            for (int ii = 0; ii < 4; ++ii) {
              int x = x0 + ii;
              bool ok = ((unsigned)y < 512u) && ((unsigned)x < 512u);
              P[jj][ii] = ok ? img[ci * 262144 + y * 512 + x] : 0.0f;
            }
          }
          #pragma unroll
          for (int ky = 0; ky < 3; ++ky) {
            #pragma unroll
            for (int kx = 0; kx < 3; ++kx) {
              float wv = cw1[c * 27 + ci * 9 + ky * 3 + kx];
              a00 = fmaf(wv, P[ky][kx],         a00);
              a01 = fmaf(wv, P[ky][kx + 1],     a01);
              a10 = fmaf(wv, P[ky + 1][kx],     a10);
              a11 = fmaf(wv, P[ky + 1][kx + 1], a11);
            }
          }
        }
        val = 0.25f * (fmaxf(a00, 0.f) + fmaxf(a01, 0.f) +
                       fmaxf(a10, 0.f) + fmaxf(a11, 0.f));
      }
      p1sh[c * 1584 + j * 264 + xx] = val;
    }
    __syncthreads();

    // ---- conv2 + relu + pool from LDS tile ----
    int ox = tid & 127;
    int oyl = tid >> 7;                    // 0 or 1
    float a[16][4];
    #pragma unroll
    for (int oc = 0; oc < 16; ++oc) {
      float bb = cb2[oc];
      a[oc][0] = bb; a[oc][1] = bb; a[oc][2] = bb; a[oc][3] = bb;
    }
    #pragma unroll
    for (int ci = 0; ci < 4; ++ci) {
      float P[4][4];
      #pragma unroll
      for (int jj = 0; jj < 4; ++jj) {
        #pragma unroll
        for (int ii = 0; ii < 4; ++ii)
          P[jj][ii] = p1sh[ci * 1584 + (2 * oyl + jj) * 264 + 2 * ox + ii];
      }
      #pragma unroll
      for (int oc = 0; oc < 16; ++oc) {
        #pragma unroll
        for (int ky = 0; ky < 3; ++ky) {
          #pragma unroll
          for (int kx = 0; kx < 3; ++kx) {
            float wv = cw2[oc * 36 + ci * 9 + ky * 3 + kx];
            a[oc][0] = fmaf(wv, P[ky][kx],         a[oc][0]);
            a[oc][1] = fmaf(wv, P[ky][kx + 1],     a[oc][1]);
            a[oc][2] = fmaf(wv, P[ky + 1][kx],     a[oc][2]);
            a[oc][3] = fmaf(wv, P[ky + 1][kx + 1], a[oc][3]);
          }
        }
      }
    }
    float x[16];
    #pragma unroll
    for (int oc = 0; oc < 16; ++oc)
      x[oc] = 0.25f * (fmaxf(a[oc][0], 0.f) + fmaxf(a[oc][1], 0.f) +
                       fmaxf(a[oc][2], 0.f) + fmaxf(a[oc][3], 0.f));

    // ---- NetVLAD softmax ----
    float p[64];
    float m = -1e30f;
    #pragma unroll
    for (int k = 0; k < 64; ++k) {
      float acc = bsh[k];
      #pragma unroll
      for (int c = 0; c < 16; ++c) acc = fmaf(wsh[k * 16 + c], x[c], acc);
      p[k] = acc;
      m = fmaxf(m, acc);
    }
    float s = 0.f;
    #pragma unroll
    for (int k = 0; k < 64; ++k) { p[k] = __expf(p[k] - m); s += p[k]; }
    float inv = 1.0f / s;
    #pragma unroll
    for (int k = 0; k < 64; ++k) p[k] *= inv;

    int q = tid >> 6, k = tid & 63;
    float acc[16];
    #pragma unroll
    for (int c = 0; c < 16; ++c) acc[c] = 0.f;
    float accA = 0.f;
    for (int pass = 0; pass < 2; ++pass) {
      __syncthreads();
      if ((tid >> 7) == pass) {
        int tt = tid & 127;
        #pragma unroll
        for (int kk = 0; kk < 64; ++kk) ps[tt * 65 + kk] = p[kk];
        #pragma unroll
        for (int c = 0; c < 16; ++c) xs[tt * 20 + c] = x[c];
      }
      __syncthreads();
      #pragma unroll
      for (int j = 0; j < 32; ++j) {
        int tt = q * 32 + j;
        float pv = ps[tt * 65 + k];
        accA += pv;
        const float4* xv = (const float4*)(xs + tt * 20);
        #pragma unroll
        for (int c4 = 0; c4 < 4; ++c4) {
          float4 xx = xv[c4];
          acc[c4 * 4 + 0] = fmaf(pv, xx.x, acc[c4 * 4 + 0]);
          acc[c4 * 4 + 1] = fmaf(pv, xx.y, acc[c4 * 4 + 1]);
          acc[c4 * 4 + 2] = fmaf(pv, xx.z, acc[c4 * 4 + 2]);
          acc[c4 * 4 + 3] = fmaf(pv, xx.w, acc[c4 * 4 + 3]);
        }
      }
    }
    __syncthreads();
    float* red = ps;                       // reuse as [256][16]
    #pragma unroll
    for (int c = 0; c < 16; ++c) red[tid * 16 + c] = acc[c];
    aS[tid] = accA;
    __syncthreads();
    if (tid == 0) {                        // gate atomics on init done
      while (uld(flag_magic) != MAGIC) __builtin_amdgcn_s_sleep(2);
    }
    __syncthreads();
    if (q == 0) {
      float aa = aS[k] + aS[64 + k] + aS[128 + k] + aS[192 + k];
      atomicAdd(&asum[k], aa);
    }
    int k2 = tid >> 2;
    int cgc = (tid & 3) * 4;
    #pragma unroll
    for (int cc = 0; cc < 4; ++cc) {
      int c = cgc + cc;
      float vv = red[(0 * 64 + k2) * 16 + c] + red[(1 * 64 + k2) * 16 + c] +
                 red[(2 * 64 + k2) * 16 + c] + red[(3 * 64 + k2) * 16 + c];
      atomicAdd(&vacc[k2 * 16 + c], vv);
    }
    __syncthreads();                       // drain atomics before tick
    if (tid == 0)
      __hip_atomic_fetch_add(vlad_done, 1u, __ATOMIC_RELAXED,
                             __HIP_MEMORY_SCOPE_AGENT);
  }
}

// ============================ K2: RNN + loss ============================
__global__ __launch_bounds__(512, 1)
void k_back(const float* __restrict__ hidw, const float* __restrict__ U,
            const float* __restrict__ feat, float* __restrict__ H,
            const float* __restrict__ outw, const float* __restrict__ outb,
            const float* __restrict__ cap,  float* __restrict__ loss) {
  __shared__ __align__(16) float smem[1100];
  const int bx  = blockIdx.x;
  const int tid = threadIdx.x;
  unsigned* Hu = (unsigned*)H;

  if (bx < 4) {
    // -------- RNN: 128 rows/block, W_h pinned in VGPRs via asm --------
    const int r   = tid >> 2;              // 0..127
    const int cg  = tid & 3;
    const int row = bx * 128 + r;
    float wrf[128];
    {
      const float4* wp = (const float4*)(hidw + row * 812 + 300 + cg * 128);
      #pragma unroll
      for (int i = 0; i < 32; ++i) {
        float4 tm = wp[i];
        wrf[4 * i + 0] = tm.x; wrf[4 * i + 1] = tm.y;
        wrf[4 * i + 2] = tm.z; wrf[4 * i + 3] = tm.w;
      }
    }
    // Opaque pin: breaks load provenance so the compiler can neither
    // rematerialize (re-load from hidw each step) nor sink the loads.
    #pragma unroll
    for (int i = 0; i < 128; ++i) asm volatile("" : "+v"(wrf[i]));
    float* buf0 = smem;          // 544 floats, swizzled (chunk k at k*136)
    float* buf1 = smem + 544;
    const int wz = (tid >> 7) * 136 + (tid & 127);
    const int wown = ((row >> 7) * 136) + (row & 127);
    const bool own = ((tid >> 7) == bx);   // cell tid produced by this block?
    buf0[wz] = feat[tid];                  // plain cached load (K1 done)
    __syncthreads();
    for (int t = 0; t < 63; ++t) {
      const float* rb = ((t & 1) ? buf1 : buf0) + cg * 136;
      float uval = (cg == 0) ? U[t * 512 + row] : 0.f;   // cached load
      float acc = 0.f;
      #pragma unroll
      for (int i = 0; i < 32; ++i) {
        float4 h4 = *(const float4*)(rb + i * 4);        // wave-broadcast
        acc = fmaf(wrf[4 * i + 0], h4.x, acc);
        acc = fmaf(wrf[4 * i + 1], h4.y, acc);
        acc = fmaf(wrf[4 * i + 2], h4.z, acc);
        acc = fmaf(wrf[4 * i + 3], h4.w, acc);
      }
      acc += __shfl_xor(acc, 1);
      acc += __shfl_xor(acc, 2);
      float hn = 0.f;
      if (cg == 0) {
        hn = sigmoidf_(acc + uval);
        fst(H + t * 512 + row, hn);
      }
      if (t < 62) {
        float* bufn = (t & 1) ? buf0 : buf1;
        if (cg == 0) bufn[wown] = hn;      // own row via LDS, no global RT
        if (!own) {                        // one cell polled per thread
          const unsigned* src = Hu + t * 512 + tid;
          unsigned aa;
          do {
            aa = uld(src);
          } while (aa == POISON);
          bufn[wz] = __uint_as_float(aa);
        }
        __syncthreads();                   // single barrier per step
      }
    }
    return;
  }

  // -------- loss block for timestep t --------
  const int t = bx - 4;
  float* hsh = smem;                       // 512
  float* red = smem + 512;                 // 8
  if (tid == 0) {
    while (uld(Hu + (size_t)t * 512) == POISON) __builtin_amdgcn_s_sleep(32);
  }
  __syncthreads();
  {
    const unsigned* src = Hu + (size_t)t * 512 + tid;
    unsigned aa;
    do {
      aa = uld(src);
    } while (aa == POISON);
    hsh[tid] = __uint_as_float(aa);
  }
  __syncthreads();
  float se = 0.f;
  if (tid < 300) {
    float acc = outb[tid];
    const float4* w4 = (const float4*)(outw + tid * 512);
    const float4* h4 = (const float4*)hsh;
    #pragma unroll 4
    for (int i = 0; i < 128; ++i) {
      float4 aa = w4[i]; float4 xx = h4[i];
      acc = fmaf(aa.x, xx.x, acc); acc = fmaf(aa.y, xx.y, acc);
      acc = fmaf(aa.z, xx.z, acc); acc = fmaf(aa.w, xx.w, acc);
    }
    float y = sigmoidf_(acc);
    float d = y - cap[(t + 1) * 300 + tid];
    se = fmaf(d, d, se);
  }
  #pragma unroll
  for (int o = 32; o > 0; o >>= 1) se += __shfl_down(se, o);
  if ((tid & 63) == 0) red[tid >> 6] = se;
  __syncthreads();
  if (tid == 0) {
    float tot = 0.f;
    #pragma unroll
    for (int qq = 0; qq < 8; ++qq) tot += red[qq];
    atomicAdd(loss, tot * (1.0f / 19200.0f));
  }
}

extern "C" void kernel_launch(void* const* d_in, const int* in_sizes, int n_in,
                              void* d_out, int out_size, void* d_ws, size_t ws_size,
                              hipStream_t stream) {
  (void)in_sizes; (void)n_in; (void)out_size; (void)ws_size;
  const float* img  = (const float*)d_in[0];   // sample 0 only
  const float* cap  = (const float*)d_in[1];   // sample 0 only
  const float* c1w  = (const float*)d_in[2];
  const float* c1b  = (const float*)d_in[3];
  const float* c2w  = (const float*)d_in[4];
  const float* c2b  = (const float*)d_in[5];
  const float* cent = (const float*)d_in[6];
  const float* nvw  = (const float*)d_in[7];
  const float* nvb  = (const float*)d_in[8];
  const float* fcw  = (const float*)d_in[9];
  const float* fcb  = (const float*)d_in[10];
  const float* hidw = (const float*)d_in[11];
  const float* hidb = (const float*)d_in[12];
  const float* outw = (const float*)d_in[13];
  const float* outb = (const float*)d_in[14];

  float* ws   = (float*)d_ws;
  float* vacc = ws;                   // 1024
  float* asum = ws + 1024;            // 64
  float* feat = ws + 1088;            // 512
  float* U    = ws + 1600;            // 63*512 = 32256
  float* H    = ws + 33856;           // 63*512 = 32256
  unsigned* flags = (unsigned*)(ws + 66112);   // [magic, vlad_done]

  k_front<<<136, 256, 0, stream>>>(img, cap, c1w, c1b, c2w, c2b, cent, nvw,
                                   nvb, fcw, fcb, hidw, hidb,
                                   vacc, asum, feat, U, H, flags,
                                   (float*)d_out);
  k_back<<<67, 512, 0, stream>>>(hidw, U, feat, H, outw, outb, cap,
                                 (float*)d_out);
}